// Round 3
// baseline (1892.018 us; speedup 1.0000x reference)
//
#include <hip/hip_runtime.h>
#include <math.h>

#define NN 20000
#define NE 320000
#define NF (NN*64)

typedef short sh8_t  __attribute__((ext_vector_type(8)));
typedef float fl4_t  __attribute__((ext_vector_type(4)));

__device__ __forceinline__ float silu_f(float x){ return x / (1.0f + expf(-x)); }

__device__ __forceinline__ short f2bf(float f){
  unsigned u = __builtin_bit_cast(unsigned, f);
  unsigned r = (u + 0x7fffu + ((u >> 16) & 1u)) >> 16;
  return (short)r;
}
__device__ __forceinline__ float bf2f(short s){
  unsigned u = ((unsigned)(unsigned short)s) << 16;
  return __builtin_bit_cast(float, u);
}

// ---- CSR build ----------------------------------------------------------
__global__ __launch_bounds__(256) void k_hist(
    const int* __restrict__ receivers, int* __restrict__ counts)
{
  int i = blockIdx.x*256 + threadIdx.x;   // 0..319999 exact
  atomicAdd(&counts[receivers[i]], 1);
}

__global__ __launch_bounds__(256) void k_scan(
    const int* __restrict__ counts, int* __restrict__ row_start, int* __restrict__ off2)
{
  __shared__ int part[256];
  __shared__ int excl[257];
  int t = threadIdx.x;
  int lo = t*79, hi = lo+79 < NN ? lo+79 : NN;
  int s = 0;
  for(int i=lo; i<hi; ++i) s += counts[i];
  part[t] = s;
  __syncthreads();
  if(t == 0){
    int a = 0;
    for(int i=0; i<256; ++i){ excl[i] = a; a += part[i]; }
    excl[256] = a;
  }
  __syncthreads();
  int a = excl[t];
  for(int i=lo; i<hi; ++i){
    int c = counts[i];
    row_start[i] = a; off2[i] = a;
    a += c;
  }
  if(t == 255) row_start[NN] = excl[256];
}

__global__ __launch_bounds__(256) void k_scatter(
    const int* __restrict__ receivers, int* __restrict__ off2, int* __restrict__ csr)
{
  int e = blockIdx.x*256 + threadIdx.x;
  int pos = atomicAdd(&off2[receivers[e]], 1);
  csr[pos] = e;
}

// ---- Fragment-ordered bf16 stream for mlp_w2 ----------------------------
__global__ __launch_bounds__(256) void k_prep_w2(
    const float* __restrict__ w2, short* __restrict__ w2f)
{
  int i = blockIdx.x*256 + threadIdx.x;     // 0..20479
  int jp   = i & 7;
  int lane = (i >> 3) & 63;
  int frag = i >> 9;                        // 0..39
  int k2 = frag / 20, p = frag % 20;
  int j = p >> 2, T = p & 3;
  int k = k2*32 + (lane >> 4)*8 + jp;
  int n = j*64 + T*16 + (lane & 15);
  w2f[i] = f2bf(w2[k*320 + n]);
}

// Transpose per-species residual weights (g-major -> f-major).
__global__ __launch_bounds__(256) void k_transpose_res(
    const float* __restrict__ Ws, const float* __restrict__ Wv,
    float* __restrict__ Wst, float* __restrict__ Wvt)
{
  int i = blockIdx.x*256 + threadIdx.x;   // 0..40959
  int spec = i >> 12;
  int g = (i >> 6) & 63;
  int f = i & 63;
  Wst[spec*4096 + f*64 + g] = Ws[i];
  Wvt[spec*4096 + f*64 + g] = Wv[i];
}

// ---- Node pre-pass: h = feats @ W_in / 8. 8 nodes per wave. --------------
__global__ __launch_bounds__(256) void k_node_pre(
    const float* __restrict__ node_feats, const float* __restrict__ W_in_s,
    const float* __restrict__ W_in_v, float* __restrict__ h_s, float* __restrict__ h_v)
{
  __shared__ float4 sh[4][8][64];
  int wave = threadIdx.x >> 6, lane = threadIdx.x & 63;
  int n0 = blockIdx.x*32 + wave*8;
  #pragma unroll
  for(int nd=0; nd<8; ++nd)
    sh[wave][nd][lane] = *(const float4*)(node_feats + ((size_t)(n0+nd)*64 + lane)*4);
  float as[8], av0[8], av1[8], av2[8];
  #pragma unroll
  for(int nd=0; nd<8; ++nd){ as[nd]=0.f; av0[nd]=0.f; av1[nd]=0.f; av2[nd]=0.f; }
  for(int f=0; f<64; ++f){
    float ws = W_in_s[f*64+lane], wv = W_in_v[f*64+lane];
    #pragma unroll
    for(int nd=0; nd<8; ++nd){
      float4 t = sh[wave][nd][f];
      as[nd]  += t.x*ws;
      av0[nd] += t.y*wv;
      av1[nd] += t.z*wv;
      av2[nd] += t.w*wv;
    }
  }
  #pragma unroll
  for(int nd=0; nd<8; ++nd){
    int o = (n0+nd)*64 + lane;
    h_s[o]      = as[nd] *0.125f;
    h_v[o]      = av0[nd]*0.125f;
    h_v[NF+o]   = av1[nd]*0.125f;
    h_v[2*NF+o] = av2[nd]*0.125f;
  }
}

// ---- Receiver-centric fused edge kernel: NO atomics ----------------------
// One wave per receiver node; its incoming edges processed in chunks of 16.
__global__ __launch_bounds__(256) void k_edge_recv(
    const float* __restrict__ vectors, const float* __restrict__ radial,
    const int* __restrict__ senders,
    const int* __restrict__ row_start, const int* __restrict__ csr,
    const float* __restrict__ mlp_w1, const short* __restrict__ w2f,
    const float* __restrict__ h_s, const float* __restrict__ h_v,
    float* __restrict__ agg_s, float* __restrict__ agg_v)
{
  __shared__ float hid[4][16][68];
  __shared__ float ey[4][16][3];
  __shared__ int   esn[4][16];
  __shared__ float rad[4][128];
  int wave = threadIdx.x >> 6, lane = threadIdx.x & 63;
  int n = blockIdx.x*4 + wave;
  int start = row_start[n], end = row_start[n+1];
  int l15 = lane & 15, q = lane >> 4;

  float w1r[8];
  #pragma unroll
  for(int r=0; r<8; ++r) w1r[r] = mlp_w1[r*64+lane];

  float accS[4]  = {0.f,0.f,0.f,0.f};
  float accV0[4] = {0.f,0.f,0.f,0.f};
  float accV1[4] = {0.f,0.f,0.f,0.f};
  float accV2[4] = {0.f,0.f,0.f,0.f};

  for(int base = start; base < end; base += 16){
    int rem = end - base;
    int cnt = rem < 16 ? rem : 16;
    // stage up to 16 edges (lanes 0..15), pad slots zeroed
    if(lane < 16){
      if(lane < cnt){
        int e = csr[base + lane];
        float4 r0 = *(const float4*)(radial + (size_t)e*8);
        float4 r1 = *(const float4*)(radial + (size_t)e*8 + 4);
        *(float4*)&rad[wave][lane*8]     = r0;
        *(float4*)&rad[wave][lane*8 + 4] = r1;
        float vx = vectors[3*e], vy = vectors[3*e+1], vz = vectors[3*e+2];
        float rinv = 1.0f/sqrtf(vx*vx + vy*vy + vz*vz + 1e-12f);
        ey[wave][lane][0] = vx*rinv; ey[wave][lane][1] = vy*rinv; ey[wave][lane][2] = vz*rinv;
        esn[wave][lane] = senders[e];
      } else {
        *(float4*)&rad[wave][lane*8]     = (float4){0.f,0.f,0.f,0.f};
        *(float4*)&rad[wave][lane*8 + 4] = (float4){0.f,0.f,0.f,0.f};
        ey[wave][lane][0]=0.f; ey[wave][lane][1]=0.f; ey[wave][lane][2]=0.f;
        esn[wave][lane] = 0;
      }
    }
    // hidden = silu(rad @ w1); pad rows are exactly zero
    #pragma unroll
    for(int t=0; t<16; ++t){
      float acc = 0.f;
      #pragma unroll
      for(int r=0; r<8; ++r) acc += rad[wave][t*8+r]*w1r[r];
      hid[wave][t][lane] = silu_f(acc);
    }
    // w = hidden @ w2 via MFMA 16x16x32 bf16, A split hi/lo
    fl4_t C[20];
    #pragma unroll
    for(int p=0; p<20; ++p) C[p] = (fl4_t){0.f,0.f,0.f,0.f};
    #pragma unroll
    for(int k2=0; k2<2; ++k2){
      const float* hp = &hid[wave][l15][k2*32 + q*8];
      sh8_t ahi, alo;
      #pragma unroll
      for(int i=0; i<8; ++i){
        float a = hp[i];
        short h = f2bf(a);
        ahi[i] = h;
        alo[i] = f2bf(a - bf2f(h));
      }
      const short* bbase = w2f + (size_t)(k2*20)*512 + lane*8;
      #pragma unroll
      for(int p=0; p<20; ++p){
        sh8_t b = *(const sh8_t*)(bbase + p*512);
        C[p] = __builtin_amdgcn_mfma_f32_16x16x32_bf16(ahi, b, C[p], 0, 0, 0);
        C[p] = __builtin_amdgcn_mfma_f32_16x16x32_bf16(alo, b, C[p], 0, 0, 0);
      }
    }
    // epilogue: rows = edges (q*4+reg), cols = T*16+l15; skip pad rows
    #pragma unroll
    for(int reg=0; reg<4; ++reg){
      int r = q*4 + reg;
      if(r < cnt){
        float y0 = ey[wave][r][0], y1 = ey[wave][r][1], y2 = ey[wave][r][2];
        int snd = esn[wave][r];
        #pragma unroll
        for(int T=0; T<4; ++T){
          int c = T*16 + l15;
          int so = snd*64 + c;
          float ss  = h_s[so];
          float sv0 = h_v[so], sv1 = h_v[NF+so], sv2 = h_v[2*NF+so];
          float dot = sv0*y0 + sv1*y1 + sv2*y2;
          float w0 = C[T][reg], w1v = C[4+T][reg], w2v = C[8+T][reg];
          float w3v = C[12+T][reg], w4v = C[16+T][reg];
          float ms  = w0*ss + w1v*dot;
          float w2s = w2v*ss;
          accS[T]  += ms;
          accV0[T] += w2s*y0 + w3v*sv0 + w4v*(sv1*y2 - sv2*y1);
          accV1[T] += w2s*y1 + w3v*sv1 + w4v*(sv2*y0 - sv0*y2);
          accV2[T] += w2s*y2 + w3v*sv2 + w4v*(sv0*y1 - sv1*y0);
        }
      }
    }
  }
  // reduce over the 4 q-groups (rows) per column
  #pragma unroll
  for(int T=0; T<4; ++T){
    accS[T]  += __shfl_xor(accS[T], 16);  accS[T]  += __shfl_xor(accS[T], 32);
    accV0[T] += __shfl_xor(accV0[T],16);  accV0[T] += __shfl_xor(accV0[T],32);
    accV1[T] += __shfl_xor(accV1[T],16);  accV1[T] += __shfl_xor(accV1[T],32);
    accV2[T] += __shfl_xor(accV2[T],16);  accV2[T] += __shfl_xor(accV2[T],32);
  }
  // lane writes column q*16 + l15 == lane
  float oS  = (q&2) ? ((q&1)?accS[3] :accS[2])  : ((q&1)?accS[1] :accS[0]);
  float oV0 = (q&2) ? ((q&1)?accV0[3]:accV0[2]) : ((q&1)?accV0[1]:accV0[0]);
  float oV1 = (q&2) ? ((q&1)?accV1[3]:accV1[2]) : ((q&1)?accV1[1]:accV1[0]);
  float oV2 = (q&2) ? ((q&1)?accV2[3]:accV2[2]) : ((q&1)?accV2[1]:accV2[0]);
  int o = n*64 + lane;
  agg_s[o]      = oS;
  agg_v[o]      = oV0;
  agg_v[NF+o]   = oV1;
  agg_v[2*NF+o] = oV2;
}

// ---- Node post-pass: 8 nodes per wave ------------------------------------
__global__ __launch_bounds__(256) void k_node_post(
  const float* __restrict__ node_feats, const int* __restrict__ specie,
  const float* __restrict__ agg_s, const float* __restrict__ agg_v,
  const float* __restrict__ Wrst, const float* __restrict__ Wrvt,
  const float* __restrict__ W_out_s, const float* __restrict__ W_out_v,
  const float* __restrict__ W_prod_s, const float* __restrict__ W_prod_v,
  const float* __restrict__ W_lin_s, const float* __restrict__ W_lin_v,
  const float* __restrict__ W_read, float* __restrict__ out_node, float* __restrict__ out_feats)
{
  __shared__ float4 buf[4][8][64];
  int wave = threadIdx.x >> 6, lane = threadIdx.x & 63;
  int n0 = blockIdx.x*32 + wave*8;
  int sp[8];
  #pragma unroll
  for(int nd=0; nd<8; ++nd) sp[nd] = specie[n0+nd];

  // Stage agg (scaled by 1/AVG_NEIGH), shared-weight matvec
  #pragma unroll
  for(int nd=0; nd<8; ++nd){
    int o = (n0+nd)*64 + lane;
    buf[wave][nd][lane] = make_float4(agg_s[o]*(1.f/16.f), agg_v[o]*(1.f/16.f),
                                      agg_v[NF+o]*(1.f/16.f), agg_v[2*NF+o]*(1.f/16.f));
  }
  float a_s[8], a0[8], a1[8], a2[8];
  #pragma unroll
  for(int nd=0; nd<8; ++nd){ a_s[nd]=0.f; a0[nd]=0.f; a1[nd]=0.f; a2[nd]=0.f; }
  for(int f=0; f<64; ++f){
    float wos = W_out_s[f*64+lane], wov = W_out_v[f*64+lane];
    #pragma unroll
    for(int nd=0; nd<8; ++nd){
      float4 t = buf[wave][nd][f];
      a_s[nd] += t.x*wos; a0[nd] += t.y*wov; a1[nd] += t.z*wov; a2[nd] += t.w*wov;
    }
  }
  #pragma unroll
  for(int nd=0; nd<8; ++nd){ a_s[nd]*=0.125f; a0[nd]*=0.125f; a1[nd]*=0.125f; a2[nd]*=0.125f; }

  // Stage node_feats; residual matvec per node (sequential species streams)
  #pragma unroll
  for(int nd=0; nd<8; ++nd)
    buf[wave][nd][lane] = *(const float4*)(node_feats + ((size_t)(n0+nd)*64 + lane)*4);
  float r_s[8], r0[8], r1[8], r2[8];
  for(int nd=0; nd<8; ++nd){
    const float* Ws_ = Wrst + sp[nd]*4096;
    const float* Wv_ = Wrvt + sp[nd]*4096;
    float rs=0.f, rv0=0.f, rv1=0.f, rv2=0.f;
    for(int f=0; f<64; ++f){
      float wrs = Ws_[f*64+lane], wrv = Wv_[f*64+lane];
      float4 t = buf[wave][nd][f];
      rs += t.x*wrs; rv0 += t.y*wrv; rv1 += t.z*wrv; rv2 += t.w*wrv;
    }
    r_s[nd]=rs*0.125f; r0[nd]=rv0*0.125f; r1[nd]=rv1*0.125f; r2[nd]=rv2*0.125f;
  }

  // Polynomial products -> buf
  #pragma unroll
  for(int nd=0; nd<8; ++nd){
    float vv = a0[nd]*a0[nd] + a1[nd]*a1[nd] + a2[nd]*a2[nd];
    float as2 = a_s[nd]*a_s[nd];
    const float* Wp = W_prod_s + sp[nd]*320;
    float p_s = Wp[lane]*a_s[nd] + Wp[64+lane]*as2 + Wp[128+lane]*as2*a_s[nd]
              + Wp[192+lane]*vv + Wp[256+lane]*a_s[nd]*vv;
    const float* Wq = W_prod_v + sp[nd]*256;
    float coef = Wq[lane] + Wq[64+lane]*a_s[nd] + Wq[128+lane]*as2 + Wq[192+lane]*vv;
    buf[wave][nd][lane] = make_float4(p_s, coef*a0[nd], coef*a1[nd], coef*a2[nd]);
  }
  float fs[8], f0[8], f1[8], f2[8];
  #pragma unroll
  for(int nd=0; nd<8; ++nd){ fs[nd]=0.f; f0[nd]=0.f; f1[nd]=0.f; f2[nd]=0.f; }
  for(int f=0; f<64; ++f){
    float wls = W_lin_s[f*64+lane], wlv = W_lin_v[f*64+lane];
    #pragma unroll
    for(int nd=0; nd<8; ++nd){
      float4 t = buf[wave][nd][f];
      fs[nd] += t.x*wls; f0[nd] += t.y*wlv; f1[nd] += t.z*wlv; f2[nd] += t.w*wlv;
    }
  }
  float wr = W_read[lane];
  #pragma unroll
  for(int nd=0; nd<8; ++nd){
    float vs = fs[nd]*0.125f + r_s[nd];
    float v0 = f0[nd]*0.125f + r0[nd];
    float v1 = f1[nd]*0.125f + r1[nd];
    float v2 = f2[nd]*0.125f + r2[nd];
    int o = (n0+nd)*64 + lane;
    float4 o4; o4.x=vs; o4.y=v0; o4.z=v1; o4.w=v2;
    *(float4*)(out_feats + (size_t)o*4) = o4;
    float x = vs * wr;
    #pragma unroll
    for(int off=32; off; off>>=1) x += __shfl_down(x, off);
    if(lane==0) out_node[n0+nd] = x*0.125f;
  }
}

extern "C" void kernel_launch(void* const* d_in, const int* in_sizes, int n_in,
                              void* d_out, int out_size, void* d_ws, size_t ws_size,
                              hipStream_t stream) {
  const float* vectors    = (const float*)d_in[0];
  const float* node_feats = (const float*)d_in[1];
  const int*   node_specie= (const int*)  d_in[2];
  const float* radial     = (const float*)d_in[3];
  const int*   senders    = (const int*)  d_in[4];
  const int*   receivers  = (const int*)  d_in[5];
  const float* W_res_s    = (const float*)d_in[6];
  const float* W_res_v    = (const float*)d_in[7];
  const float* W_in_s     = (const float*)d_in[8];
  const float* W_in_v     = (const float*)d_in[9];
  const float* mlp_w1     = (const float*)d_in[10];
  const float* mlp_w2     = (const float*)d_in[11];
  const float* W_out_s    = (const float*)d_in[12];
  const float* W_out_v    = (const float*)d_in[13];
  const float* W_prod_s   = (const float*)d_in[14];
  const float* W_prod_v   = (const float*)d_in[15];
  const float* W_lin_s    = (const float*)d_in[16];
  const float* W_lin_v    = (const float*)d_in[17];
  const float* W_read     = (const float*)d_in[18];

  float* ws    = (float*)d_ws;
  float* h_s   = ws;                          // NF
  float* h_v   = ws + NF;                     // 3*NF
  float* agg_s = ws + 4*(size_t)NF;           // NF
  float* agg_v = ws + 5*(size_t)NF;           // 3*NF
  float* Wrst  = ws + 8*(size_t)NF;           // 40960
  float* Wrvt  = ws + 8*(size_t)NF + 40960;   // 40960
  short* w2f   = (short*)(ws + 8*(size_t)NF + 81920);  // 20480 shorts
  int*   ibase = (int*)(ws + 8*(size_t)NF + 81920 + 10240);
  int*   row_start = ibase;                   // NN+1
  int*   off2      = ibase + (NN+1);          // NN (also histogram counts)
  int*   csr       = ibase + (NN+1) + NN;     // NE

  hipMemsetAsync(off2, 0, (size_t)NN*sizeof(int), stream);
  k_hist<<<NE/256, 256, 0, stream>>>(receivers, off2);
  // k_scan reads counts from off2 and rewrites off2 with offsets (safe: each
  // thread reads counts[i] into a register before overwriting).
  k_scan<<<1, 256, 0, stream>>>(off2, row_start, off2);
  k_scatter<<<NE/256, 256, 0, stream>>>(receivers, off2, csr);
  k_prep_w2<<<80, 256, 0, stream>>>(mlp_w2, w2f);
  k_transpose_res<<<160, 256, 0, stream>>>(W_res_s, W_res_v, Wrst, Wrvt);
  k_node_pre<<<625, 256, 0, stream>>>(node_feats, W_in_s, W_in_v, h_s, h_v);
  k_edge_recv<<<NN/4, 256, 0, stream>>>(vectors, radial, senders, row_start, csr,
                                        mlp_w1, w2f, h_s, h_v, agg_s, agg_v);
  k_node_post<<<625, 256, 0, stream>>>(node_feats, node_specie, agg_s, agg_v,
                                       Wrst, Wrvt, W_out_s, W_out_v,
                                       W_prod_s, W_prod_v, W_lin_s, W_lin_v,
                                       W_read, (float*)d_out, (float*)d_out + NN);
}

// Round 4
// 557.561 us; speedup vs baseline: 3.3934x; 3.3934x over previous
//
#include <hip/hip_runtime.h>
#include <math.h>

#define NN 20000
#define NE 320000
#define NF (NN*64)

typedef short sh8_t  __attribute__((ext_vector_type(8)));
typedef float fl4_t  __attribute__((ext_vector_type(4)));

__device__ __forceinline__ float silu_f(float x){ return x / (1.0f + expf(-x)); }

__device__ __forceinline__ short f2bf(float f){
  unsigned u = __builtin_bit_cast(unsigned, f);
  unsigned r = (u + 0x7fffu + ((u >> 16) & 1u)) >> 16;
  return (short)r;
}
__device__ __forceinline__ float bf2f(short s){
  unsigned u = ((unsigned)(unsigned short)s) << 16;
  return __builtin_bit_cast(float, u);
}

// ---- CSR build ----------------------------------------------------------
__global__ __launch_bounds__(256) void k_hist(
    const int* __restrict__ receivers, int* __restrict__ counts)
{
  int i = blockIdx.x*256 + threadIdx.x;   // 0..319999 exact
  atomicAdd(&counts[receivers[i]], 1);
}

__global__ __launch_bounds__(256) void k_scan(
    const int* __restrict__ counts, int* __restrict__ row_start, int* __restrict__ off2)
{
  __shared__ int part[256];
  __shared__ int excl[257];
  int t = threadIdx.x;
  int lo = t*79, hi = lo+79 < NN ? lo+79 : NN;
  int s = 0;
  for(int i=lo; i<hi; ++i) s += counts[i];
  part[t] = s;
  __syncthreads();
  if(t == 0){
    int a = 0;
    for(int i=0; i<256; ++i){ excl[i] = a; a += part[i]; }
    excl[256] = a;
  }
  __syncthreads();
  int a = excl[t];
  for(int i=lo; i<hi; ++i){
    int c = counts[i];
    row_start[i] = a; off2[i] = a;
    a += c;
  }
  if(t == 255) row_start[NN] = excl[256];
}

__global__ __launch_bounds__(256) void k_scatter(
    const int* __restrict__ receivers, int* __restrict__ off2, int* __restrict__ csr)
{
  int e = blockIdx.x*256 + threadIdx.x;
  int pos = atomicAdd(&off2[receivers[e]], 1);
  csr[pos] = e;
}

// ---- Fragment-ordered bf16 stream for mlp_w2 ----------------------------
__global__ __launch_bounds__(256) void k_prep_w2(
    const float* __restrict__ w2, short* __restrict__ w2f)
{
  int i = blockIdx.x*256 + threadIdx.x;     // 0..20479
  int jp   = i & 7;
  int lane = (i >> 3) & 63;
  int frag = i >> 9;                        // 0..39
  int k2 = frag / 20, p = frag % 20;
  int j = p >> 2, T = p & 3;
  int k = k2*32 + (lane >> 4)*8 + jp;
  int n = j*64 + T*16 + (lane & 15);
  w2f[i] = f2bf(w2[k*320 + n]);
}

// Transpose per-species residual weights (g-major -> f-major).
__global__ __launch_bounds__(256) void k_transpose_res(
    const float* __restrict__ Ws, const float* __restrict__ Wv,
    float* __restrict__ Wst, float* __restrict__ Wvt)
{
  int i = blockIdx.x*256 + threadIdx.x;   // 0..40959
  int spec = i >> 12;
  int g = (i >> 6) & 63;
  int f = i & 63;
  Wst[spec*4096 + f*64 + g] = Ws[i];
  Wvt[spec*4096 + f*64 + g] = Wv[i];
}

// ---- Node pre-pass (R1 known-good): one wave per node --------------------
__global__ __launch_bounds__(256) void k_node_pre(
    const float* __restrict__ node_feats, const float* __restrict__ W_in_s,
    const float* __restrict__ W_in_v, float* __restrict__ h_s, float* __restrict__ h_v)
{
  __shared__ float sh[4][4][64];
  int wave = threadIdx.x >> 6, lane = threadIdx.x & 63;
  int n = blockIdx.x*4 + wave;
  int o = n*64 + lane;
  float4 nf = *(const float4*)(node_feats + (size_t)o*4);
  sh[wave][0][lane]=nf.x; sh[wave][1][lane]=nf.y; sh[wave][2][lane]=nf.z; sh[wave][3][lane]=nf.w;
  __syncthreads();
  float as=0.f, av0=0.f, av1=0.f, av2=0.f;
  #pragma unroll 8
  for(int f=0; f<64; ++f){
    float ws = W_in_s[f*64+lane], wv = W_in_v[f*64+lane];
    as  += sh[wave][0][f]*ws;
    av0 += sh[wave][1][f]*wv;
    av1 += sh[wave][2][f]*wv;
    av2 += sh[wave][3][f]*wv;
  }
  h_s[o]      = as *0.125f;
  h_v[o]      = av0*0.125f;
  h_v[NF+o]   = av1*0.125f;
  h_v[2*NF+o] = av2*0.125f;
}

// ---- Receiver-centric fused edge kernel: NO atomics ----------------------
__global__ __launch_bounds__(256) void k_edge_recv(
    const float* __restrict__ vectors, const float* __restrict__ radial,
    const int* __restrict__ senders,
    const int* __restrict__ row_start, const int* __restrict__ csr,
    const float* __restrict__ mlp_w1, const short* __restrict__ w2f,
    const float* __restrict__ h_s, const float* __restrict__ h_v,
    float* __restrict__ agg_s, float* __restrict__ agg_v)
{
  __shared__ float hid[4][16][68];
  __shared__ float ey[4][16][3];
  __shared__ int   esn[4][16];
  __shared__ float rad[4][128];
  int wave = threadIdx.x >> 6, lane = threadIdx.x & 63;
  int n = blockIdx.x*4 + wave;
  int start = row_start[n], end = row_start[n+1];
  int l15 = lane & 15, q = lane >> 4;

  float w1r[8];
  #pragma unroll
  for(int r=0; r<8; ++r) w1r[r] = mlp_w1[r*64+lane];

  float accS[4]  = {0.f,0.f,0.f,0.f};
  float accV0[4] = {0.f,0.f,0.f,0.f};
  float accV1[4] = {0.f,0.f,0.f,0.f};
  float accV2[4] = {0.f,0.f,0.f,0.f};

  for(int base = start; base < end; base += 16){
    int rem = end - base;
    int cnt = rem < 16 ? rem : 16;
    if(lane < 16){
      if(lane < cnt){
        int e = csr[base + lane];
        float4 r0 = *(const float4*)(radial + (size_t)e*8);
        float4 r1 = *(const float4*)(radial + (size_t)e*8 + 4);
        *(float4*)&rad[wave][lane*8]     = r0;
        *(float4*)&rad[wave][lane*8 + 4] = r1;
        float vx = vectors[3*e], vy = vectors[3*e+1], vz = vectors[3*e+2];
        float rinv = 1.0f/sqrtf(vx*vx + vy*vy + vz*vz + 1e-12f);
        ey[wave][lane][0] = vx*rinv; ey[wave][lane][1] = vy*rinv; ey[wave][lane][2] = vz*rinv;
        esn[wave][lane] = senders[e];
      } else {
        *(float4*)&rad[wave][lane*8]     = (float4){0.f,0.f,0.f,0.f};
        *(float4*)&rad[wave][lane*8 + 4] = (float4){0.f,0.f,0.f,0.f};
        ey[wave][lane][0]=0.f; ey[wave][lane][1]=0.f; ey[wave][lane][2]=0.f;
        esn[wave][lane] = 0;
      }
    }
    #pragma unroll
    for(int t=0; t<16; ++t){
      float acc = 0.f;
      #pragma unroll
      for(int r=0; r<8; ++r) acc += rad[wave][t*8+r]*w1r[r];
      hid[wave][t][lane] = silu_f(acc);
    }
    fl4_t C[20];
    #pragma unroll
    for(int p=0; p<20; ++p) C[p] = (fl4_t){0.f,0.f,0.f,0.f};
    #pragma unroll
    for(int k2=0; k2<2; ++k2){
      const float* hp = &hid[wave][l15][k2*32 + q*8];
      sh8_t ahi, alo;
      #pragma unroll
      for(int i=0; i<8; ++i){
        float a = hp[i];
        short h = f2bf(a);
        ahi[i] = h;
        alo[i] = f2bf(a - bf2f(h));
      }
      const short* bbase = w2f + (size_t)(k2*20)*512 + lane*8;
      #pragma unroll
      for(int p=0; p<20; ++p){
        sh8_t b = *(const sh8_t*)(bbase + p*512);
        C[p] = __builtin_amdgcn_mfma_f32_16x16x32_bf16(ahi, b, C[p], 0, 0, 0);
        C[p] = __builtin_amdgcn_mfma_f32_16x16x32_bf16(alo, b, C[p], 0, 0, 0);
      }
    }
    #pragma unroll
    for(int reg=0; reg<4; ++reg){
      int r = q*4 + reg;
      if(r < cnt){
        float y0 = ey[wave][r][0], y1 = ey[wave][r][1], y2 = ey[wave][r][2];
        int snd = esn[wave][r];
        #pragma unroll
        for(int T=0; T<4; ++T){
          int c = T*16 + l15;
          int so = snd*64 + c;
          float ss  = h_s[so];
          float sv0 = h_v[so], sv1 = h_v[NF+so], sv2 = h_v[2*NF+so];
          float dot = sv0*y0 + sv1*y1 + sv2*y2;
          float w0 = C[T][reg], w1v = C[4+T][reg], w2v = C[8+T][reg];
          float w3v = C[12+T][reg], w4v = C[16+T][reg];
          float ms  = w0*ss + w1v*dot;
          float w2s = w2v*ss;
          accS[T]  += ms;
          accV0[T] += w2s*y0 + w3v*sv0 + w4v*(sv1*y2 - sv2*y1);
          accV1[T] += w2s*y1 + w3v*sv1 + w4v*(sv2*y0 - sv0*y2);
          accV2[T] += w2s*y2 + w3v*sv2 + w4v*(sv0*y1 - sv1*y0);
        }
      }
    }
  }
  #pragma unroll
  for(int T=0; T<4; ++T){
    accS[T]  += __shfl_xor(accS[T], 16);  accS[T]  += __shfl_xor(accS[T], 32);
    accV0[T] += __shfl_xor(accV0[T],16);  accV0[T] += __shfl_xor(accV0[T],32);
    accV1[T] += __shfl_xor(accV1[T],16);  accV1[T] += __shfl_xor(accV1[T],32);
    accV2[T] += __shfl_xor(accV2[T],16);  accV2[T] += __shfl_xor(accV2[T],32);
  }
  float oS  = (q&2) ? ((q&1)?accS[3] :accS[2])  : ((q&1)?accS[1] :accS[0]);
  float oV0 = (q&2) ? ((q&1)?accV0[3]:accV0[2]) : ((q&1)?accV0[1]:accV0[0]);
  float oV1 = (q&2) ? ((q&1)?accV1[3]:accV1[2]) : ((q&1)?accV1[1]:accV1[0]);
  float oV2 = (q&2) ? ((q&1)?accV2[3]:accV2[2]) : ((q&1)?accV2[1]:accV2[0]);
  int o = n*64 + lane;
  agg_s[o]      = oS;
  agg_v[o]      = oV0;
  agg_v[NF+o]   = oV1;
  agg_v[2*NF+o] = oV2;
}

// ---- Node post-pass (R1 known-good): one wave per node -------------------
__global__ __launch_bounds__(256) void k_node_post(
  const float* __restrict__ node_feats, const int* __restrict__ specie,
  const float* __restrict__ agg_s, const float* __restrict__ agg_v,
  const float* __restrict__ Wrst, const float* __restrict__ Wrvt,
  const float* __restrict__ W_out_s, const float* __restrict__ W_out_v,
  const float* __restrict__ W_prod_s, const float* __restrict__ W_prod_v,
  const float* __restrict__ W_lin_s, const float* __restrict__ W_lin_v,
  const float* __restrict__ W_read, float* __restrict__ out_node, float* __restrict__ out_feats)
{
  __shared__ float shA[4][4][64];
  __shared__ float shS[4][4][64];
  __shared__ float shP[4][4][64];
  int wave = threadIdx.x >> 6, lane = threadIdx.x & 63;
  int n = blockIdx.x*4 + wave;
  int o = n*64 + lane;
  shA[wave][0][lane] = agg_s[o]      * (1.f/16.f);
  shA[wave][1][lane] = agg_v[o]      * (1.f/16.f);
  shA[wave][2][lane] = agg_v[NF+o]   * (1.f/16.f);
  shA[wave][3][lane] = agg_v[2*NF+o] * (1.f/16.f);
  float4 nf = *(const float4*)(node_feats + (size_t)o*4);
  shS[wave][0][lane]=nf.x; shS[wave][1][lane]=nf.y; shS[wave][2][lane]=nf.z; shS[wave][3][lane]=nf.w;
  __syncthreads();
  int spec = specie[n];
  const float* Ws_ = Wrst + spec*4096;
  const float* Wv_ = Wrvt + spec*4096;
  float a_s=0.f,a0=0.f,a1=0.f,a2=0.f, r_s=0.f,r0=0.f,r1=0.f,r2=0.f;
  #pragma unroll 4
  for(int f=0; f<64; ++f){
    float wos=W_out_s[f*64+lane], wov=W_out_v[f*64+lane];
    a_s += shA[wave][0][f]*wos;
    a0  += shA[wave][1][f]*wov;
    a1  += shA[wave][2][f]*wov;
    a2  += shA[wave][3][f]*wov;
    float wrs=Ws_[f*64+lane], wrv=Wv_[f*64+lane];
    r_s += shS[wave][0][f]*wrs;
    r0  += shS[wave][1][f]*wrv;
    r1  += shS[wave][2][f]*wrv;
    r2  += shS[wave][3][f]*wrv;
  }
  a_s*=0.125f; a0*=0.125f; a1*=0.125f; a2*=0.125f;
  r_s*=0.125f; r0*=0.125f; r1*=0.125f; r2*=0.125f;
  float vv = a0*a0 + a1*a1 + a2*a2;
  float as2 = a_s*a_s;
  const float* Wp = W_prod_s + spec*320;
  float p_s = Wp[lane]*a_s + Wp[64+lane]*as2 + Wp[128+lane]*as2*a_s
            + Wp[192+lane]*vv + Wp[256+lane]*a_s*vv;
  const float* Wq = W_prod_v + spec*256;
  float coef = Wq[lane] + Wq[64+lane]*a_s + Wq[128+lane]*as2 + Wq[192+lane]*vv;
  shP[wave][0][lane] = p_s;
  shP[wave][1][lane] = coef*a0;
  shP[wave][2][lane] = coef*a1;
  shP[wave][3][lane] = coef*a2;
  __syncthreads();
  float fs=0.f,f0=0.f,f1=0.f,f2=0.f;
  #pragma unroll 4
  for(int f=0; f<64; ++f){
    float wls=W_lin_s[f*64+lane], wlv=W_lin_v[f*64+lane];
    fs += shP[wave][0][f]*wls;
    f0 += shP[wave][1][f]*wlv;
    f1 += shP[wave][2][f]*wlv;
    f2 += shP[wave][3][f]*wlv;
  }
  fs = fs*0.125f + r_s;
  f0 = f0*0.125f + r0;
  f1 = f1*0.125f + r1;
  f2 = f2*0.125f + r2;
  float x = fs * W_read[lane];
  #pragma unroll
  for(int off=32; off; off>>=1) x += __shfl_down(x, off);
  if(lane==0) out_node[n] = x*0.125f;
  float4 o4; o4.x=fs; o4.y=f0; o4.z=f1; o4.w=f2;
  *(float4*)(out_feats + (size_t)o*4) = o4;
}

extern "C" void kernel_launch(void* const* d_in, const int* in_sizes, int n_in,
                              void* d_out, int out_size, void* d_ws, size_t ws_size,
                              hipStream_t stream) {
  const float* vectors    = (const float*)d_in[0];
  const float* node_feats = (const float*)d_in[1];
  const int*   node_specie= (const int*)  d_in[2];
  const float* radial     = (const float*)d_in[3];
  const int*   senders    = (const int*)  d_in[4];
  const int*   receivers  = (const int*)  d_in[5];
  const float* W_res_s    = (const float*)d_in[6];
  const float* W_res_v    = (const float*)d_in[7];
  const float* W_in_s     = (const float*)d_in[8];
  const float* W_in_v     = (const float*)d_in[9];
  const float* mlp_w1     = (const float*)d_in[10];
  const float* mlp_w2     = (const float*)d_in[11];
  const float* W_out_s    = (const float*)d_in[12];
  const float* W_out_v    = (const float*)d_in[13];
  const float* W_prod_s   = (const float*)d_in[14];
  const float* W_prod_v   = (const float*)d_in[15];
  const float* W_lin_s    = (const float*)d_in[16];
  const float* W_lin_v    = (const float*)d_in[17];
  const float* W_read     = (const float*)d_in[18];

  float* ws    = (float*)d_ws;
  float* h_s   = ws;                          // NF
  float* h_v   = ws + NF;                     // 3*NF
  float* agg_s = ws + 4*(size_t)NF;           // NF
  float* agg_v = ws + 5*(size_t)NF;           // 3*NF
  float* Wrst  = ws + 8*(size_t)NF;           // 40960
  float* Wrvt  = ws + 8*(size_t)NF + 40960;   // 40960
  short* w2f   = (short*)(ws + 8*(size_t)NF + 81920);  // 20480 shorts
  int*   ibase = (int*)(ws + 8*(size_t)NF + 81920 + 10240);
  int*   row_start = ibase;                   // NN+1
  int*   off2      = ibase + (NN+1);          // NN (histogram counts then offsets)
  int*   csr       = ibase + (NN+1) + NN;     // NE

  hipMemsetAsync(off2, 0, (size_t)NN*sizeof(int), stream);
  k_hist<<<NE/256, 256, 0, stream>>>(receivers, off2);
  k_scan<<<1, 256, 0, stream>>>(off2, row_start, off2);
  k_scatter<<<NE/256, 256, 0, stream>>>(receivers, off2, csr);
  k_prep_w2<<<80, 256, 0, stream>>>(mlp_w2, w2f);
  k_transpose_res<<<160, 256, 0, stream>>>(W_res_s, W_res_v, Wrst, Wrvt);
  k_node_pre<<<NN/4, 256, 0, stream>>>(node_feats, W_in_s, W_in_v, h_s, h_v);
  k_edge_recv<<<NN/4, 256, 0, stream>>>(vectors, radial, senders, row_start, csr,
                                        mlp_w1, w2f, h_s, h_v, agg_s, agg_v);
  k_node_post<<<NN/4, 256, 0, stream>>>(node_feats, node_specie, agg_s, agg_v,
                                        Wrst, Wrvt, W_out_s, W_out_v,
                                        W_prod_s, W_prod_v, W_lin_s, W_lin_v,
                                        W_read, (float*)d_out, (float*)d_out + NN);
}